// Round 16
// baseline (192.963 us; speedup 1.0000x reference)
//
#include <hip/hip_runtime.h>
#include <hip/hip_bf16.h>

#define BB   4
#define NN   8192
#define EE   65536
#define FOBS 128
#define FH   256
#define FOUT 1024
#define NLOG 18
#define P20  20
#define BKT  64

typedef __attribute__((ext_vector_type(8))) short frag8;
typedef __attribute__((ext_vector_type(4))) float f32x4;

__device__ __forceinline__ ushort f2b(float v) {
    __hip_bfloat16 h = __float2bfloat16(v);
    return *reinterpret_cast<ushort*>(&h);
}
__device__ __forceinline__ float blo(uint u) { return __uint_as_float(u << 16); }
__device__ __forceinline__ float bhi(uint u) { return __uint_as_float(u & 0xffff0000u); }

// ---------------- prep: weight transposes + heads pack + cursor zero ----------------
#define W0_N   (FOBS * FH)
#define W1_N   (FH * FOUT)
#define WH_N   (19 * FOUT)
#define CUR_N  (BB * NN)
#define PREP_TOTAL (W0_N + W1_N + WH_N + CUR_N)

__global__ void prep_kernel(const float* __restrict__ W0, ushort* __restrict__ W0T,
                            const float* __restrict__ W1, ushort* __restrict__ W1T,
                            const float* __restrict__ Wl, const float* __restrict__ Wv,
                            ushort* __restrict__ WT19, int* __restrict__ cursor) {
    int idx = blockIdx.x * blockDim.x + threadIdx.x;
    if (idx < W0_N) {
        int n = idx / FOBS, k = idx - n * FOBS;
        W0T[idx] = f2b(W0[(size_t)k * FH + n]);
        return;
    }
    idx -= W0_N;
    if (idx < W1_N) {
        int n = idx / FH, k = idx - n * FH;
        W1T[idx] = f2b(W1[(size_t)k * FOUT + n]);
        return;
    }
    idx -= W1_N;
    if (idx < WH_N) {
        int o = idx >> 10, k = idx & (FOUT - 1);
        WT19[idx] = f2b((o < NLOG) ? Wl[(size_t)k * NLOG + o] : Wv[k]);
        return;
    }
    idx -= WH_N;
    if (idx < CUR_N) cursor[idx] = 0;
}

// ---------------- bucket fill: direct atomic slot allocation ----------------
__global__ void bucket_fill(const int* __restrict__ edges, int* __restrict__ cursor,
                            int* __restrict__ bucket) {
    int blk = blockIdx.x;
    int xcd = blk & 7;
    int g = xcd >> 1;
    int chunk = (blk >> 3) * 2 + (xcd & 1);
    int e = chunk * 256 + threadIdx.x;
    const int* src = edges + (size_t)g * 2 * EE;
    const int* dst = src + EE;
    int d = dst[e];
    int slot = atomicAdd(&cursor[(size_t)g * NN + d], 1);
    if (slot < BKT) bucket[((size_t)g * NN + d) * BKT + slot] = src[e];
}

// ---------------- gathers: wave-per-node, masked 8-wide groups, dinv on the fly ----------------
__global__ __launch_bounds__(256) void gather_agg_f32(
    const float* __restrict__ x_all, const int* __restrict__ cnt_all,
    const int* __restrict__ bucket, uint* __restrict__ agg_all)
{
    int g = blockIdx.y;
    int wv = threadIdx.x >> 6, lane = threadIdx.x & 63;
    int n = blockIdx.x * 4 + wv;
    const float2* x = (const float2*)(x_all + (size_t)g * NN * FOBS);
    const int* cnt = cnt_all + (size_t)g * NN;
    const int* bkt = bucket + ((size_t)g * NN + n) * BKT;

    int cn = cnt[n];
    float wn = rsqrtf((float)cn + 1.0f);
    int deg = min(cn, BKT);

    float2 self = x[(size_t)n * 64 + lane];
    float ax = wn * wn * self.x, ay = wn * wn * self.y;

    for (int i = 0; i < deg; i += 8) {
        int last = deg - 1;
        int s0 = bkt[i];
        int s1 = bkt[min(i + 1, last)], s2 = bkt[min(i + 2, last)], s3 = bkt[min(i + 3, last)];
        int s4 = bkt[min(i + 4, last)], s5 = bkt[min(i + 5, last)], s6 = bkt[min(i + 6, last)];
        int s7 = bkt[min(i + 7, last)];
        float w0 = rsqrtf((float)cnt[s0] + 1.0f) * wn;
        float w1 = (i + 1 < deg) ? rsqrtf((float)cnt[s1] + 1.0f) * wn : 0.0f;
        float w2 = (i + 2 < deg) ? rsqrtf((float)cnt[s2] + 1.0f) * wn : 0.0f;
        float w3 = (i + 3 < deg) ? rsqrtf((float)cnt[s3] + 1.0f) * wn : 0.0f;
        float w4 = (i + 4 < deg) ? rsqrtf((float)cnt[s4] + 1.0f) * wn : 0.0f;
        float w5 = (i + 5 < deg) ? rsqrtf((float)cnt[s5] + 1.0f) * wn : 0.0f;
        float w6 = (i + 6 < deg) ? rsqrtf((float)cnt[s6] + 1.0f) * wn : 0.0f;
        float w7 = (i + 7 < deg) ? rsqrtf((float)cnt[s7] + 1.0f) * wn : 0.0f;
        float2 r0 = x[(size_t)s0 * 64 + lane], r1 = x[(size_t)s1 * 64 + lane];
        float2 r2 = x[(size_t)s2 * 64 + lane], r3 = x[(size_t)s3 * 64 + lane];
        float2 r4 = x[(size_t)s4 * 64 + lane], r5 = x[(size_t)s5 * 64 + lane];
        float2 r6 = x[(size_t)s6 * 64 + lane], r7 = x[(size_t)s7 * 64 + lane];
        ax += w0 * r0.x + w1 * r1.x + w2 * r2.x + w3 * r3.x
            + w4 * r4.x + w5 * r5.x + w6 * r6.x + w7 * r7.x;
        ay += w0 * r0.y + w1 * r1.y + w2 * r2.y + w3 * r3.y
            + w4 * r4.y + w5 * r5.y + w6 * r6.y + w7 * r7.y;
    }
    agg_all[((size_t)g * NN + n) * 64 + lane] = (uint)f2b(ax) | ((uint)f2b(ay) << 16);
}

__global__ __launch_bounds__(256) void gather_agg_b256(
    const uint2* __restrict__ xb_all, const int* __restrict__ cnt_all,
    const int* __restrict__ bucket, uint2* __restrict__ agg_all)
{
    int g = blockIdx.y;
    int wv = threadIdx.x >> 6, lane = threadIdx.x & 63;
    int n = blockIdx.x * 4 + wv;
    const uint2* xb = xb_all + (size_t)g * NN * 64;
    const int* cnt = cnt_all + (size_t)g * NN;
    const int* bkt = bucket + ((size_t)g * NN + n) * BKT;

    int cn = cnt[n];
    float wn = rsqrtf((float)cn + 1.0f);
    int deg = min(cn, BKT);

    uint2 u = xb[(size_t)n * 64 + lane];
    float w2s = wn * wn;
    float a0 = w2s * blo(u.x), a1 = w2s * bhi(u.x), a2 = w2s * blo(u.y), a3 = w2s * bhi(u.y);

    for (int i = 0; i < deg; i += 8) {
        int last = deg - 1;
        int s0 = bkt[i];
        int s1 = bkt[min(i + 1, last)], s2 = bkt[min(i + 2, last)], s3 = bkt[min(i + 3, last)];
        int s4 = bkt[min(i + 4, last)], s5 = bkt[min(i + 5, last)], s6 = bkt[min(i + 6, last)];
        int s7 = bkt[min(i + 7, last)];
        float w0 = rsqrtf((float)cnt[s0] + 1.0f) * wn;
        float w1 = (i + 1 < deg) ? rsqrtf((float)cnt[s1] + 1.0f) * wn : 0.0f;
        float w2 = (i + 2 < deg) ? rsqrtf((float)cnt[s2] + 1.0f) * wn : 0.0f;
        float w3 = (i + 3 < deg) ? rsqrtf((float)cnt[s3] + 1.0f) * wn : 0.0f;
        float w4 = (i + 4 < deg) ? rsqrtf((float)cnt[s4] + 1.0f) * wn : 0.0f;
        float w5 = (i + 5 < deg) ? rsqrtf((float)cnt[s5] + 1.0f) * wn : 0.0f;
        float w6 = (i + 6 < deg) ? rsqrtf((float)cnt[s6] + 1.0f) * wn : 0.0f;
        float w7 = (i + 7 < deg) ? rsqrtf((float)cnt[s7] + 1.0f) * wn : 0.0f;
        uint2 r0 = xb[(size_t)s0 * 64 + lane], r1 = xb[(size_t)s1 * 64 + lane];
        uint2 r2 = xb[(size_t)s2 * 64 + lane], r3 = xb[(size_t)s3 * 64 + lane];
        uint2 r4 = xb[(size_t)s4 * 64 + lane], r5 = xb[(size_t)s5 * 64 + lane];
        uint2 r6 = xb[(size_t)s6 * 64 + lane], r7 = xb[(size_t)s7 * 64 + lane];
        a0 += w0 * blo(r0.x) + w1 * blo(r1.x) + w2 * blo(r2.x) + w3 * blo(r3.x)
            + w4 * blo(r4.x) + w5 * blo(r5.x) + w6 * blo(r6.x) + w7 * blo(r7.x);
        a1 += w0 * bhi(r0.x) + w1 * bhi(r1.x) + w2 * bhi(r2.x) + w3 * bhi(r3.x)
            + w4 * bhi(r4.x) + w5 * bhi(r5.x) + w6 * bhi(r6.x) + w7 * bhi(r7.x);
        a2 += w0 * blo(r0.y) + w1 * blo(r1.y) + w2 * blo(r2.y) + w3 * blo(r3.y)
            + w4 * blo(r4.y) + w5 * blo(r5.y) + w6 * blo(r6.y) + w7 * blo(r7.y);
        a3 += w0 * bhi(r0.y) + w1 * bhi(r1.y) + w2 * bhi(r2.y) + w3 * bhi(r3.y)
            + w4 * bhi(r4.y) + w5 * bhi(r5.y) + w6 * bhi(r6.y) + w7 * bhi(r7.y);
    }
    uint2 o;
    o.x = (uint)f2b(a0) | ((uint)f2b(a1) << 16);
    o.y = (uint)f2b(a2) | ((uint)f2b(a3) << 16);
    agg_all[((size_t)g * NN + n) * 64 + lane] = o;
}

// ---------------- MFMA GEMM (layer 1, batched via blockIdx.z) ----------------
__global__ __launch_bounds__(256) void mfma_gemm(
    const ushort* __restrict__ A_all, const ushort* __restrict__ BT,
    const float* __restrict__ bias, ushort* __restrict__ C_all,
    int M, int N, int K, int relu)
{
    __shared__ ushort As[128][72];
    __shared__ ushort Bs[128][72];

    int g = blockIdx.z;
    const ushort* A = A_all + (size_t)g * M * K;
    ushort* C = C_all + (size_t)g * M * N;

    int t = threadIdx.x;
    int bn = blockIdx.x, bm = blockIdx.y;
    int lane = t & 63, w = t >> 6;
    int wm = w >> 1, wn = w & 1;
    int l15 = lane & 15, quad = lane >> 4;

    f32x4 acc[4][4] = {};

    int srow = t >> 3, scol = (t & 7) * 8;
    const ushort* Abase = A + (size_t)(bm * 128) * K;
    const ushort* Bbase = BT + (size_t)(bn * 128) * K;

    for (int k0 = 0; k0 < K; k0 += 64) {
#pragma unroll
        for (int i = 0; i < 4; ++i) {
            int row = srow + 32 * i;
            *(uint4*)&As[row][scol] = *(const uint4*)(Abase + (size_t)row * K + k0 + scol);
        }
#pragma unroll
        for (int i = 0; i < 4; ++i) {
            int row = srow + 32 * i;
            *(uint4*)&Bs[row][scol] = *(const uint4*)(Bbase + (size_t)row * K + k0 + scol);
        }
        __syncthreads();
#pragma unroll
        for (int kk = 0; kk < 64; kk += 32) {
            frag8 af[4], bf[4];
#pragma unroll
            for (int i = 0; i < 4; ++i)
                af[i] = *(const frag8*)&As[wm * 64 + i * 16 + l15][kk + quad * 8];
#pragma unroll
            for (int j = 0; j < 4; ++j)
                bf[j] = *(const frag8*)&Bs[wn * 64 + j * 16 + l15][kk + quad * 8];
#pragma unroll
            for (int i = 0; i < 4; ++i)
#pragma unroll
                for (int j = 0; j < 4; ++j)
                    acc[i][j] = __builtin_amdgcn_mfma_f32_16x16x32_bf16(af[i], bf[j], acc[i][j], 0, 0, 0);
        }
        __syncthreads();
    }

#pragma unroll
    for (int i = 0; i < 4; ++i) {
#pragma unroll
        for (int j = 0; j < 4; ++j) {
            int col = bn * 128 + wn * 64 + j * 16 + l15;
            float bcol = bias[col];
#pragma unroll
            for (int r = 0; r < 4; ++r) {
                int row = bm * 128 + wm * 64 + i * 16 + quad * 4 + r;
                float v = acc[i][j][r] + bcol;
                if (relu) v = fmaxf(v, 0.0f);
                C[(size_t)row * N + col] = f2b(v);
            }
        }
    }
}

// ---------------- fused layer-2 GEMM + heads, BK=128 (v3) ----------------
// Same v1 structure (2 blocks/CU) but full K=256 staged in 2 rounds instead of 4:
// dynamic LDS 73.3 KB (As/Bs [128][136], Ct overlays As, wt [20][136]).
// Occupancy: 160/73.3 = 2 blocks/CU (unchanged vs v1); barriers ~24 vs ~40.
#define V3_AS  0
#define V3_BS  17408            // 128*136
#define V3_CT  0                // overlays As (exactly 128*136)
#define V3_WT  34816            // 20*136 = 2720
#define V3_SHORTS 37536         // 75072 bytes

__global__ __launch_bounds__(256) void gemm2_heads_v3(
    const ushort* __restrict__ hagg_all,  // [g][NN][FH] bf16
    const ushort* __restrict__ W1T,       // [FOUT][FH] bf16
    const float*  __restrict__ b1,        // [FOUT]
    const ushort* __restrict__ WT19,      // [19][FOUT] bf16
    float* __restrict__ partial)          // [2][BB][NN][P20] f32
{
    extern __shared__ __align__(16) ushort smem[];
    ushort* As = smem + V3_AS;            // [128][136]
    ushort* Bs = smem + V3_BS;            // [128][136]
    ushort* Ct = smem + V3_CT;            // [128][136] (overlays As)
    ushort* wt = smem + V3_WT;            // [20][136]

    int bm = blockIdx.x, sp = blockIdx.y, g = blockIdx.z;
    int t = threadIdx.x;
    int lane = t & 63, w = t >> 6;
    int wm = w >> 1, wn = w & 1;
    int l15 = lane & 15, quad = lane >> 4;
    int srow = t >> 4, scol = (t & 15) * 8;   // 16 thr/row, 16B each (128 k-cols/round)

    const ushort* A0 = hagg_all + ((size_t)g * NN + bm * 128) * FH;

    if (t < 136) wt[19 * 136 + t] = 0;    // zero pad row once

    f32x4 hacc[2][2] = {};

    for (int bi = 0; bi < 4; ++bi) {
        int bn = sp * 4 + bi;
        __syncthreads();   // previous iter's heads reads of Ct/wt complete

        // stage WT19 slice rows 0..18 (cols bn*128..+128)
        for (int idx = t; idx < 19 * 16; idx += 256) {
            int row = idx >> 4, c8 = (idx & 15) * 8;
            *(uint4*)&wt[row * 136 + c8] = *(const uint4*)(WT19 + (size_t)row * FOUT + bn * 128 + c8);
        }

        f32x4 acc[4][4] = {};
        const ushort* Bbase = W1T + (size_t)(bn * 128) * FH;

        for (int k0 = 0; k0 < FH; k0 += 128) {   // BK=128: 2 staging rounds
#pragma unroll
            for (int i = 0; i < 8; ++i) {
                int row = srow + 16 * i;
                *(uint4*)&As[row * 136 + scol] = *(const uint4*)(A0 + (size_t)row * FH + k0 + scol);
                *(uint4*)&Bs[row * 136 + scol] = *(const uint4*)(Bbase + (size_t)row * FH + k0 + scol);
            }
            __syncthreads();
#pragma unroll
            for (int kk = 0; kk < 128; kk += 32) {
                frag8 af[4], bf[4];
#pragma unroll
                for (int i = 0; i < 4; ++i)
                    af[i] = *(const frag8*)&As[(wm * 64 + i * 16 + l15) * 136 + kk + quad * 8];
#pragma unroll
                for (int j = 0; j < 4; ++j)
                    bf[j] = *(const frag8*)&Bs[(wn * 64 + j * 16 + l15) * 136 + kk + quad * 8];
#pragma unroll
                for (int i = 0; i < 4; ++i)
#pragma unroll
                    for (int j = 0; j < 4; ++j)
                        acc[i][j] = __builtin_amdgcn_mfma_f32_16x16x32_bf16(af[i], bf[j], acc[i][j], 0, 0, 0);
            }
            __syncthreads();   // all waves done with As/Bs (also guards Ct overwrite)
        }

        // epilogue: bias + relu -> bf16 -> Ctile
#pragma unroll
        for (int j = 0; j < 4; ++j) {
            int colL = wn * 64 + j * 16 + l15;
            float bcol = b1[bn * 128 + colL];
#pragma unroll
            for (int i = 0; i < 4; ++i) {
                int rowL = wm * 64 + i * 16 + quad * 4;
#pragma unroll
                for (int r = 0; r < 4; ++r) {
                    float v = fmaxf(acc[i][j][r] + bcol, 0.0f);
                    Ct[(size_t)(rowL + r) * 136 + colL] = f2b(v);
                }
            }
        }
        __syncthreads();

        // heads: wave w owns m-tiles 2w, 2w+1 (16 rows each)
        int r1 = (l15 < 3) ? (16 + l15) : 19;
#pragma unroll
        for (int kk = 0; kk < 128; kk += 32) {
            frag8 b0 = *(const frag8*)&wt[l15 * 136 + kk + quad * 8];
            frag8 bO = *(const frag8*)&wt[r1 * 136 + kk + quad * 8];
#pragma unroll
            for (int mt = 0; mt < 2; ++mt) {
                int row = (w * 2 + mt) * 16 + l15;
                frag8 af = *(const frag8*)&Ct[(size_t)row * 136 + kk + quad * 8];
                hacc[mt][0] = __builtin_amdgcn_mfma_f32_16x16x32_bf16(af, b0, hacc[mt][0], 0, 0, 0);
                hacc[mt][1] = __builtin_amdgcn_mfma_f32_16x16x32_bf16(af, bO, hacc[mt][1], 0, 0, 0);
            }
        }
        // loop-top sync guards Ct/wt reuse
    }

#pragma unroll
    for (int mt = 0; mt < 2; ++mt) {
#pragma unroll
        for (int r = 0; r < 4; ++r) {
            int node = bm * 128 + (w * 2 + mt) * 16 + quad * 4 + r;
            size_t base = ((size_t)(sp * BB + g) * NN + node) * P20;
            partial[base + l15] = hacc[mt][0][r];
            if (l15 < 3) partial[base + 16 + l15] = hacc[mt][1][r];
        }
    }
}

// ---------------- heads combine: out = p0 + p1 + bias ----------------
__global__ void heads_combine(const float* __restrict__ partial,
                              const float* __restrict__ bl, const float* __restrict__ bv,
                              float* __restrict__ out_logits, float* __restrict__ out_values) {
    int i = blockIdx.x * blockDim.x + threadIdx.x;
    if (i >= BB * NN * 19) return;
    int o = i % 19;
    int gn = i / 19;
    float v = partial[(size_t)gn * P20 + o] + partial[((size_t)BB * NN + gn) * P20 + o];
    if (o < NLOG) out_logits[(size_t)gn * NLOG + o] = v + bl[o];
    else          out_values[gn] = v + bv[0];
}

// ---------------- launcher ----------------
extern "C" void kernel_launch(void* const* d_in, const int* in_sizes, int n_in,
                              void* d_out, int out_size, void* d_ws, size_t ws_size,
                              hipStream_t stream) {
    const float* nodes = (const float*)d_in[0];
    const int*   edges = (const int*)d_in[1];
    const float* W0 = (const float*)d_in[2];
    const float* b0 = (const float*)d_in[3];
    const float* W1 = (const float*)d_in[4];
    const float* b1 = (const float*)d_in[5];
    const float* Wl = (const float*)d_in[6];
    const float* bl = (const float*)d_in[7];
    const float* Wv = (const float*)d_in[8];
    const float* bv = (const float*)d_in[9];

    float* out_logits = (float*)d_out;
    float* out_values = out_logits + (size_t)BB * NN * NLOG;

    char* ws = (char*)d_ws;
    int*    cursor  = (int*)(ws);                     // 128 KB (becomes cnt)
    ushort* W0T     = (ushort*)(ws + (128 << 10));    // 64 KB
    ushort* W1T     = (ushort*)(ws + (192 << 10));    // 512 KB
    ushort* WT19    = (ushort*)(ws + (704 << 10));    // 38 KB
    int*    bucket  = (int*)(ws + (1u << 20));        // 8 MB   [B,N,64]
    ushort* xagg_b  = (ushort*)(ws + (9u << 20));     // 8 MB   [B,N,128]
    ushort* h1b     = (ushort*)(ws + (17u << 20));    // 16 MB  [B,N,256]
    ushort* hagg_b  = (ushort*)(ws + (33u << 20));    // 16 MB  [B,N,256]
    float*  partial = (float*)(ws + (49u << 20));     // 5.25 MB [2,B,N,20]
    // total ~55 MB

    // dynamic-LDS cap for v3 (73.3 KB > 64 KB default); idempotent host-side call
    hipFuncSetAttribute((const void*)gemm2_heads_v3,
                        hipFuncAttributeMaxDynamicSharedMemorySize,
                        V3_SHORTS * 2);

    // 1. prep
    prep_kernel<<<(PREP_TOTAL + 255) / 256, 256, 0, stream>>>(
        W0, W0T, W1, W1T, Wl, Wv, WT19, cursor);

    // 2. bucket fill
    bucket_fill<<<1024, 256, 0, stream>>>(edges, cursor, bucket);

    // 3. layer-1 aggregation
    gather_agg_f32<<<dim3(NN / 4, BB), 256, 0, stream>>>(nodes, cursor, bucket, (uint*)xagg_b);

    // 4. layer-1 GEMM
    mfma_gemm<<<dim3(FH / 128, NN / 128, BB), 256, 0, stream>>>(
        xagg_b, W0T, b0, h1b, NN, FH, FOBS, 1);

    // 5. layer-2 aggregation
    gather_agg_b256<<<dim3(NN / 4, BB), 256, 0, stream>>>((const uint2*)h1b, cursor, bucket,
                                                          (uint2*)hagg_b);

    // 6. fused layer-2 GEMM + heads (BK=128, 2 blocks/CU)
    gemm2_heads_v3<<<dim3(NN / 128, 2, BB), 256, V3_SHORTS * 2, stream>>>(
        hagg_b, W1T, b1, WT19, partial);

    // 7. combine
    heads_combine<<<(BB * NN * 19 + 255) / 256, 256, 0, stream>>>(partial, bl, bv,
                                                                  out_logits, out_values);
}

// Round 17
// 192.896 us; speedup vs baseline: 1.0003x; 1.0003x over previous
//
#include <hip/hip_runtime.h>
#include <hip/hip_bf16.h>

#define BB   4
#define NN   8192
#define EE   65536
#define FOBS 128
#define FH   256
#define FOUT 1024
#define NLOG 18
#define P20  20
#define BKT  64

typedef __attribute__((ext_vector_type(8))) short frag8;
typedef __attribute__((ext_vector_type(4))) float f32x4;

__device__ __forceinline__ ushort f2b(float v) {
    __hip_bfloat16 h = __float2bfloat16(v);
    return *reinterpret_cast<ushort*>(&h);
}
__device__ __forceinline__ float blo(uint u) { return __uint_as_float(u << 16); }
__device__ __forceinline__ float bhi(uint u) { return __uint_as_float(u & 0xffff0000u); }

// ---------------- prep: node cast + weight transposes + heads pack + cursor zero ----------------
#define NODES_N (BB * NN * FOBS / 4)         // 1048576 float4 groups
#define W0_N   (FOBS * FH)
#define W1_N   (FH * FOUT)
#define WH_N   (19 * FOUT)
#define CUR_N  (BB * NN)
#define PREP_TOTAL (NODES_N + W0_N + W1_N + WH_N + CUR_N)

__global__ void prep_kernel(const float* __restrict__ nodes, ushort* __restrict__ nodes_b,
                            const float* __restrict__ W0, ushort* __restrict__ W0T,
                            const float* __restrict__ W1, ushort* __restrict__ W1T,
                            const float* __restrict__ Wl, const float* __restrict__ Wv,
                            ushort* __restrict__ WT19, int* __restrict__ cursor) {
    int idx = blockIdx.x * blockDim.x + threadIdx.x;
    if (idx < NODES_N) {
        float4 v = *(const float4*)(nodes + 4 * (size_t)idx);
        ushort4 o;
        o.x = f2b(v.x); o.y = f2b(v.y); o.z = f2b(v.z); o.w = f2b(v.w);
        *(ushort4*)(nodes_b + 4 * (size_t)idx) = o;
        return;
    }
    idx -= NODES_N;
    if (idx < W0_N) {
        int n = idx / FOBS, k = idx - n * FOBS;
        W0T[idx] = f2b(W0[(size_t)k * FH + n]);
        return;
    }
    idx -= W0_N;
    if (idx < W1_N) {
        int n = idx / FH, k = idx - n * FH;
        W1T[idx] = f2b(W1[(size_t)k * FOUT + n]);
        return;
    }
    idx -= W1_N;
    if (idx < WH_N) {
        int o = idx >> 10, k = idx & (FOUT - 1);
        WT19[idx] = f2b((o < NLOG) ? Wl[(size_t)k * NLOG + o] : Wv[k]);
        return;
    }
    idx -= WH_N;
    if (idx < CUR_N) cursor[idx] = 0;
}

// ---------------- bucket fill: direct atomic slot allocation ----------------
__global__ void bucket_fill(const int* __restrict__ edges, int* __restrict__ cursor,
                            int* __restrict__ bucket) {
    int blk = blockIdx.x;
    int xcd = blk & 7;
    int g = xcd >> 1;
    int chunk = (blk >> 3) * 2 + (xcd & 1);
    int e = chunk * 256 + threadIdx.x;
    const int* src = edges + (size_t)g * 2 * EE;
    const int* dst = src + EE;
    int d = dst[e];
    int slot = atomicAdd(&cursor[(size_t)g * NN + d], 1);
    if (slot < BKT) bucket[((size_t)g * NN + d) * BKT + slot] = src[e];
}

// ---------------- gather layer 1: bf16 rows of 128 (uint per lane), masked 8-wide ----------------
__global__ __launch_bounds__(256) void gather_agg_b128(
    const uint* __restrict__ xb_all, const int* __restrict__ cnt_all,
    const int* __restrict__ bucket, uint* __restrict__ agg_all)
{
    int g = blockIdx.y;
    int wv = threadIdx.x >> 6, lane = threadIdx.x & 63;
    int n = blockIdx.x * 4 + wv;
    const uint* xb = xb_all + (size_t)g * NN * 64;   // 64 uint per row of 128 bf16
    const int* cnt = cnt_all + (size_t)g * NN;
    const int* bkt = bucket + ((size_t)g * NN + n) * BKT;

    int cn = cnt[n];
    float wn = rsqrtf((float)cn + 1.0f);
    int deg = min(cn, BKT);

    uint u = xb[(size_t)n * 64 + lane];
    float ax = wn * wn * blo(u), ay = wn * wn * bhi(u);

    for (int i = 0; i < deg; i += 8) {
        int last = deg - 1;
        int s0 = bkt[i];
        int s1 = bkt[min(i + 1, last)], s2 = bkt[min(i + 2, last)], s3 = bkt[min(i + 3, last)];
        int s4 = bkt[min(i + 4, last)], s5 = bkt[min(i + 5, last)], s6 = bkt[min(i + 6, last)];
        int s7 = bkt[min(i + 7, last)];
        float w0 = rsqrtf((float)cnt[s0] + 1.0f) * wn;
        float w1 = (i + 1 < deg) ? rsqrtf((float)cnt[s1] + 1.0f) * wn : 0.0f;
        float w2 = (i + 2 < deg) ? rsqrtf((float)cnt[s2] + 1.0f) * wn : 0.0f;
        float w3 = (i + 3 < deg) ? rsqrtf((float)cnt[s3] + 1.0f) * wn : 0.0f;
        float w4 = (i + 4 < deg) ? rsqrtf((float)cnt[s4] + 1.0f) * wn : 0.0f;
        float w5 = (i + 5 < deg) ? rsqrtf((float)cnt[s5] + 1.0f) * wn : 0.0f;
        float w6 = (i + 6 < deg) ? rsqrtf((float)cnt[s6] + 1.0f) * wn : 0.0f;
        float w7 = (i + 7 < deg) ? rsqrtf((float)cnt[s7] + 1.0f) * wn : 0.0f;
        uint r0 = xb[(size_t)s0 * 64 + lane], r1 = xb[(size_t)s1 * 64 + lane];
        uint r2 = xb[(size_t)s2 * 64 + lane], r3 = xb[(size_t)s3 * 64 + lane];
        uint r4 = xb[(size_t)s4 * 64 + lane], r5 = xb[(size_t)s5 * 64 + lane];
        uint r6 = xb[(size_t)s6 * 64 + lane], r7 = xb[(size_t)s7 * 64 + lane];
        ax += w0 * blo(r0) + w1 * blo(r1) + w2 * blo(r2) + w3 * blo(r3)
            + w4 * blo(r4) + w5 * blo(r5) + w6 * blo(r6) + w7 * blo(r7);
        ay += w0 * bhi(r0) + w1 * bhi(r1) + w2 * bhi(r2) + w3 * bhi(r3)
            + w4 * bhi(r4) + w5 * bhi(r5) + w6 * bhi(r6) + w7 * bhi(r7);
    }
    agg_all[((size_t)g * NN + n) * 64 + lane] = (uint)f2b(ax) | ((uint)f2b(ay) << 16);
}

// ---------------- gather layer 2: bf16 rows of 256 (uint2 per lane), masked 8-wide ----------------
__global__ __launch_bounds__(256) void gather_agg_b256(
    const uint2* __restrict__ xb_all, const int* __restrict__ cnt_all,
    const int* __restrict__ bucket, uint2* __restrict__ agg_all)
{
    int g = blockIdx.y;
    int wv = threadIdx.x >> 6, lane = threadIdx.x & 63;
    int n = blockIdx.x * 4 + wv;
    const uint2* xb = xb_all + (size_t)g * NN * 64;
    const int* cnt = cnt_all + (size_t)g * NN;
    const int* bkt = bucket + ((size_t)g * NN + n) * BKT;

    int cn = cnt[n];
    float wn = rsqrtf((float)cn + 1.0f);
    int deg = min(cn, BKT);

    uint2 u = xb[(size_t)n * 64 + lane];
    float w2s = wn * wn;
    float a0 = w2s * blo(u.x), a1 = w2s * bhi(u.x), a2 = w2s * blo(u.y), a3 = w2s * bhi(u.y);

    for (int i = 0; i < deg; i += 8) {
        int last = deg - 1;
        int s0 = bkt[i];
        int s1 = bkt[min(i + 1, last)], s2 = bkt[min(i + 2, last)], s3 = bkt[min(i + 3, last)];
        int s4 = bkt[min(i + 4, last)], s5 = bkt[min(i + 5, last)], s6 = bkt[min(i + 6, last)];
        int s7 = bkt[min(i + 7, last)];
        float w0 = rsqrtf((float)cnt[s0] + 1.0f) * wn;
        float w1 = (i + 1 < deg) ? rsqrtf((float)cnt[s1] + 1.0f) * wn : 0.0f;
        float w2 = (i + 2 < deg) ? rsqrtf((float)cnt[s2] + 1.0f) * wn : 0.0f;
        float w3 = (i + 3 < deg) ? rsqrtf((float)cnt[s3] + 1.0f) * wn : 0.0f;
        float w4 = (i + 4 < deg) ? rsqrtf((float)cnt[s4] + 1.0f) * wn : 0.0f;
        float w5 = (i + 5 < deg) ? rsqrtf((float)cnt[s5] + 1.0f) * wn : 0.0f;
        float w6 = (i + 6 < deg) ? rsqrtf((float)cnt[s6] + 1.0f) * wn : 0.0f;
        float w7 = (i + 7 < deg) ? rsqrtf((float)cnt[s7] + 1.0f) * wn : 0.0f;
        uint2 r0 = xb[(size_t)s0 * 64 + lane], r1 = xb[(size_t)s1 * 64 + lane];
        uint2 r2 = xb[(size_t)s2 * 64 + lane], r3 = xb[(size_t)s3 * 64 + lane];
        uint2 r4 = xb[(size_t)s4 * 64 + lane], r5 = xb[(size_t)s5 * 64 + lane];
        uint2 r6 = xb[(size_t)s6 * 64 + lane], r7 = xb[(size_t)s7 * 64 + lane];
        a0 += w0 * blo(r0.x) + w1 * blo(r1.x) + w2 * blo(r2.x) + w3 * blo(r3.x)
            + w4 * blo(r4.x) + w5 * blo(r5.x) + w6 * blo(r6.x) + w7 * blo(r7.x);
        a1 += w0 * bhi(r0.x) + w1 * bhi(r1.x) + w2 * bhi(r2.x) + w3 * bhi(r3.x)
            + w4 * bhi(r4.x) + w5 * bhi(r5.x) + w6 * bhi(r6.x) + w7 * bhi(r7.x);
        a2 += w0 * blo(r0.y) + w1 * blo(r1.y) + w2 * blo(r2.y) + w3 * blo(r3.y)
            + w4 * blo(r4.y) + w5 * blo(r5.y) + w6 * blo(r6.y) + w7 * blo(r7.y);
        a3 += w0 * bhi(r0.y) + w1 * bhi(r1.y) + w2 * bhi(r2.y) + w3 * bhi(r3.y)
            + w4 * bhi(r4.y) + w5 * bhi(r5.y) + w6 * bhi(r6.y) + w7 * bhi(r7.y);
    }
    uint2 o;
    o.x = (uint)f2b(a0) | ((uint)f2b(a1) << 16);
    o.y = (uint)f2b(a2) | ((uint)f2b(a3) << 16);
    agg_all[((size_t)g * NN + n) * 64 + lane] = o;
}

// ---------------- MFMA GEMM (layer 1, batched via blockIdx.z) ----------------
__global__ __launch_bounds__(256) void mfma_gemm(
    const ushort* __restrict__ A_all, const ushort* __restrict__ BT,
    const float* __restrict__ bias, ushort* __restrict__ C_all,
    int M, int N, int K, int relu)
{
    __shared__ ushort As[128][72];
    __shared__ ushort Bs[128][72];

    int g = blockIdx.z;
    const ushort* A = A_all + (size_t)g * M * K;
    ushort* C = C_all + (size_t)g * M * N;

    int t = threadIdx.x;
    int bn = blockIdx.x, bm = blockIdx.y;
    int lane = t & 63, w = t >> 6;
    int wm = w >> 1, wn = w & 1;
    int l15 = lane & 15, quad = lane >> 4;

    f32x4 acc[4][4] = {};

    int srow = t >> 3, scol = (t & 7) * 8;
    const ushort* Abase = A + (size_t)(bm * 128) * K;
    const ushort* Bbase = BT + (size_t)(bn * 128) * K;

    for (int k0 = 0; k0 < K; k0 += 64) {
#pragma unroll
        for (int i = 0; i < 4; ++i) {
            int row = srow + 32 * i;
            *(uint4*)&As[row][scol] = *(const uint4*)(Abase + (size_t)row * K + k0 + scol);
        }
#pragma unroll
        for (int i = 0; i < 4; ++i) {
            int row = srow + 32 * i;
            *(uint4*)&Bs[row][scol] = *(const uint4*)(Bbase + (size_t)row * K + k0 + scol);
        }
        __syncthreads();
#pragma unroll
        for (int kk = 0; kk < 64; kk += 32) {
            frag8 af[4], bf[4];
#pragma unroll
            for (int i = 0; i < 4; ++i)
                af[i] = *(const frag8*)&As[wm * 64 + i * 16 + l15][kk + quad * 8];
#pragma unroll
            for (int j = 0; j < 4; ++j)
                bf[j] = *(const frag8*)&Bs[wn * 64 + j * 16 + l15][kk + quad * 8];
#pragma unroll
            for (int i = 0; i < 4; ++i)
#pragma unroll
                for (int j = 0; j < 4; ++j)
                    acc[i][j] = __builtin_amdgcn_mfma_f32_16x16x32_bf16(af[i], bf[j], acc[i][j], 0, 0, 0);
        }
        __syncthreads();
    }

#pragma unroll
    for (int i = 0; i < 4; ++i) {
#pragma unroll
        for (int j = 0; j < 4; ++j) {
            int col = bn * 128 + wn * 64 + j * 16 + l15;
            float bcol = bias[col];
#pragma unroll
            for (int r = 0; r < 4; ++r) {
                int row = bm * 128 + wm * 64 + i * 16 + quad * 4 + r;
                float v = acc[i][j][r] + bcol;
                if (relu) v = fmaxf(v, 0.0f);
                C[(size_t)row * N + col] = f2b(v);
            }
        }
    }
}

// ---------------- fused layer-2 GEMM + heads (v1: 2 blocks/CU, 8 waves/CU) ----------------
__global__ __launch_bounds__(256) void gemm2_heads(
    const ushort* __restrict__ hagg_all,  // [g][NN][FH] bf16
    const ushort* __restrict__ W1T,       // [FOUT][FH] bf16
    const float*  __restrict__ b1,        // [FOUT]
    const ushort* __restrict__ WT19,      // [19][FOUT] bf16
    float* __restrict__ partial)          // [2][BB][NN][P20] f32
{
    __shared__ __align__(16) ushort smem[2 * 128 * 72];  // As|Bs; reused as Ctile
    __shared__ __align__(16) ushort wt[20][136];         // WT19 slice, row19=0

    ushort* As = smem;
    ushort* Bs = smem + 128 * 72;
    ushort* Ct = smem;                                   // [128][136]

    int bm = blockIdx.x, sp = blockIdx.y, g = blockIdx.z;
    int t = threadIdx.x;
    int lane = t & 63, w = t >> 6;
    int wm = w >> 1, wn = w & 1;
    int l15 = lane & 15, quad = lane >> 4;
    int srow = t >> 3, scol = (t & 7) * 8;

    const ushort* A0 = hagg_all + ((size_t)g * NN + bm * 128) * FH;

    if (t < 136) wt[19][t] = 0;

    f32x4 hacc[2][2] = {};

    for (int bi = 0; bi < 4; ++bi) {
        int bn = sp * 4 + bi;
        __syncthreads();

        for (int idx = t; idx < 19 * 16; idx += 256) {
            int row = idx >> 4, c8 = (idx & 15) * 8;
            *(uint4*)&wt[row][c8] = *(const uint4*)(WT19 + (size_t)row * FOUT + bn * 128 + c8);
        }

        f32x4 acc[4][4] = {};
        const ushort* Bbase = W1T + (size_t)(bn * 128) * FH;

        for (int k0 = 0; k0 < FH; k0 += 64) {
#pragma unroll
            for (int i = 0; i < 4; ++i) {
                int row = srow + 32 * i;
                *(uint4*)&As[row * 72 + scol] = *(const uint4*)(A0 + (size_t)row * FH + k0 + scol);
                *(uint4*)&Bs[row * 72 + scol] = *(const uint4*)(Bbase + (size_t)row * FH + k0 + scol);
            }
            __syncthreads();
#pragma unroll
            for (int kk = 0; kk < 64; kk += 32) {
                frag8 af[4], bf[4];
#pragma unroll
                for (int i = 0; i < 4; ++i)
                    af[i] = *(const frag8*)&As[(wm * 64 + i * 16 + l15) * 72 + kk + quad * 8];
#pragma unroll
                for (int j = 0; j < 4; ++j)
                    bf[j] = *(const frag8*)&Bs[(wn * 64 + j * 16 + l15) * 72 + kk + quad * 8];
#pragma unroll
                for (int i = 0; i < 4; ++i)
#pragma unroll
                    for (int j = 0; j < 4; ++j)
                        acc[i][j] = __builtin_amdgcn_mfma_f32_16x16x32_bf16(af[i], bf[j], acc[i][j], 0, 0, 0);
            }
            __syncthreads();
        }

#pragma unroll
        for (int j = 0; j < 4; ++j) {
            int colL = wn * 64 + j * 16 + l15;
            float bcol = b1[bn * 128 + colL];
#pragma unroll
            for (int i = 0; i < 4; ++i) {
                int rowL = wm * 64 + i * 16 + quad * 4;
#pragma unroll
                for (int r = 0; r < 4; ++r) {
                    float v = fmaxf(acc[i][j][r] + bcol, 0.0f);
                    Ct[(size_t)(rowL + r) * 136 + colL] = f2b(v);
                }
            }
        }
        __syncthreads();

        int r1 = (l15 < 3) ? (16 + l15) : 19;
#pragma unroll
        for (int kk = 0; kk < 128; kk += 32) {
            frag8 b0 = *(const frag8*)&wt[l15][kk + quad * 8];
            frag8 bO = *(const frag8*)&wt[r1][kk + quad * 8];
#pragma unroll
            for (int mt = 0; mt < 2; ++mt) {
                int row = (w * 2 + mt) * 16 + l15;
                frag8 af = *(const frag8*)&Ct[(size_t)row * 136 + kk + quad * 8];
                hacc[mt][0] = __builtin_amdgcn_mfma_f32_16x16x32_bf16(af, b0, hacc[mt][0], 0, 0, 0);
                hacc[mt][1] = __builtin_amdgcn_mfma_f32_16x16x32_bf16(af, bO, hacc[mt][1], 0, 0, 0);
            }
        }
    }

#pragma unroll
    for (int mt = 0; mt < 2; ++mt) {
#pragma unroll
        for (int r = 0; r < 4; ++r) {
            int node = bm * 128 + (w * 2 + mt) * 16 + quad * 4 + r;
            size_t base = ((size_t)(sp * BB + g) * NN + node) * P20;
            partial[base + l15] = hacc[mt][0][r];
            if (l15 < 3) partial[base + 16 + l15] = hacc[mt][1][r];
        }
    }
}

// ---------------- heads combine: out = p0 + p1 + bias ----------------
__global__ void heads_combine(const float* __restrict__ partial,
                              const float* __restrict__ bl, const float* __restrict__ bv,
                              float* __restrict__ out_logits, float* __restrict__ out_values) {
    int i = blockIdx.x * blockDim.x + threadIdx.x;
    if (i >= BB * NN * 19) return;
    int o = i % 19;
    int gn = i / 19;
    float v = partial[(size_t)gn * P20 + o] + partial[((size_t)BB * NN + gn) * P20 + o];
    if (o < NLOG) out_logits[(size_t)gn * NLOG + o] = v + bl[o];
    else          out_values[gn] = v + bv[0];
}

// ---------------- launcher ----------------
extern "C" void kernel_launch(void* const* d_in, const int* in_sizes, int n_in,
                              void* d_out, int out_size, void* d_ws, size_t ws_size,
                              hipStream_t stream) {
    const float* nodes = (const float*)d_in[0];
    const int*   edges = (const int*)d_in[1];
    const float* W0 = (const float*)d_in[2];
    const float* b0 = (const float*)d_in[3];
    const float* W1 = (const float*)d_in[4];
    const float* b1 = (const float*)d_in[5];
    const float* Wl = (const float*)d_in[6];
    const float* bl = (const float*)d_in[7];
    const float* Wv = (const float*)d_in[8];
    const float* bv = (const float*)d_in[9];

    float* out_logits = (float*)d_out;
    float* out_values = out_logits + (size_t)BB * NN * NLOG;

    char* ws = (char*)d_ws;
    int*    cursor  = (int*)(ws);                     // 128 KB (becomes cnt)
    ushort* W0T     = (ushort*)(ws + (128 << 10));    // 64 KB
    ushort* W1T     = (ushort*)(ws + (192 << 10));    // 512 KB
    ushort* WT19    = (ushort*)(ws + (704 << 10));    // 38 KB
    int*    bucket  = (int*)(ws + (1u << 20));        // 8 MB   [B,N,64]
    ushort* xagg_b  = (ushort*)(ws + (9u << 20));     // 8 MB   [B,N,128]
    ushort* h1b     = (ushort*)(ws + (17u << 20));    // 16 MB  [B,N,256]
    ushort* hagg_b  = (ushort*)(ws + (33u << 20));    // 16 MB  [B,N,256]
    float*  partial = (float*)(ws + (49u << 20));     // 5.25 MB [2,B,N,20]
    ushort* nodes_b = (ushort*)(ws + (56u << 20));    // 8 MB   [B,N,128] bf16
    // total ~64 MB

    // 1. prep (node cast + weights + cursor zero)
    prep_kernel<<<(PREP_TOTAL + 255) / 256, 256, 0, stream>>>(
        nodes, nodes_b, W0, W0T, W1, W1T, Wl, Wv, WT19, cursor);

    // 2. bucket fill
    bucket_fill<<<1024, 256, 0, stream>>>(edges, cursor, bucket);

    // 3. layer-1 aggregation (bf16 rows: 4 cache lines/row vs 8 for f32)
    gather_agg_b128<<<dim3(NN / 4, BB), 256, 0, stream>>>((const uint*)nodes_b, cursor, bucket,
                                                          (uint*)xagg_b);

    // 4. layer-1 GEMM
    mfma_gemm<<<dim3(FH / 128, NN / 128, BB), 256, 0, stream>>>(
        xagg_b, W0T, b0, h1b, NN, FH, FOBS, 1);

    // 5. layer-2 aggregation
    gather_agg_b256<<<dim3(NN / 4, BB), 256, 0, stream>>>((const uint2*)h1b, cursor, bucket,
                                                          (uint2*)hagg_b);

    // 6. fused layer-2 GEMM + heads (h2 stays in LDS)
    gemm2_heads<<<dim3(NN / 128, 2, BB), 256, 0, stream>>>(hagg_b, W1T, b1, WT19, partial);

    // 7. combine
    heads_combine<<<(BB * NN * 19 + 255) / 256, 256, 0, stream>>>(partial, bl, bv,
                                                                  out_logits, out_values);
}

// Round 19
// 191.738 us; speedup vs baseline: 1.0064x; 1.0060x over previous
//
#include <hip/hip_runtime.h>
#include <hip/hip_bf16.h>

#define BB   4
#define NN   8192
#define EE   65536
#define FOBS 128
#define FH   256
#define FOUT 1024
#define NLOG 18
#define P20  20
#define BKT  64

typedef __attribute__((ext_vector_type(8))) short frag8;
typedef __attribute__((ext_vector_type(4))) float f32x4;

__device__ __forceinline__ ushort f2b(float v) {
    __hip_bfloat16 h = __float2bfloat16(v);
    return *reinterpret_cast<ushort*>(&h);
}
__device__ __forceinline__ float blo(uint u) { return __uint_as_float(u << 16); }
__device__ __forceinline__ float bhi(uint u) { return __uint_as_float(u & 0xffff0000u); }

// ---------------- prep: weight transposes + heads pack + cursor zero ----------------
#define W0_N   (FOBS * FH)
#define W1_N   (FH * FOUT)
#define WH_N   (19 * FOUT)
#define CUR_N  (BB * NN)
#define PREP_TOTAL (W0_N + W1_N + WH_N + CUR_N)

__global__ void prep_kernel(const float* __restrict__ W0, ushort* __restrict__ W0T,
                            const float* __restrict__ W1, ushort* __restrict__ W1T,
                            const float* __restrict__ Wl, const float* __restrict__ Wv,
                            ushort* __restrict__ WT19, int* __restrict__ cursor) {
    int idx = blockIdx.x * blockDim.x + threadIdx.x;
    if (idx < W0_N) {
        int n = idx / FOBS, k = idx - n * FOBS;
        W0T[idx] = f2b(W0[(size_t)k * FH + n]);
        return;
    }
    idx -= W0_N;
    if (idx < W1_N) {
        int n = idx / FH, k = idx - n * FH;
        W1T[idx] = f2b(W1[(size_t)k * FOUT + n]);
        return;
    }
    idx -= W1_N;
    if (idx < WH_N) {
        int o = idx >> 10, k = idx & (FOUT - 1);
        WT19[idx] = f2b((o < NLOG) ? Wl[(size_t)k * NLOG + o] : Wv[k]);
        return;
    }
    idx -= WH_N;
    if (idx < CUR_N) cursor[idx] = 0;
}

// ---------------- bucket fill: direct atomic slot allocation ----------------
__global__ void bucket_fill(const int* __restrict__ edges, int* __restrict__ cursor,
                            int* __restrict__ bucket) {
    int blk = blockIdx.x;
    int xcd = blk & 7;
    int g = xcd >> 1;
    int chunk = (blk >> 3) * 2 + (xcd & 1);
    int e = chunk * 256 + threadIdx.x;
    const int* src = edges + (size_t)g * 2 * EE;
    const int* dst = src + EE;
    int d = dst[e];
    int slot = atomicAdd(&cursor[(size_t)g * NN + d], 1);
    if (slot < BKT) bucket[((size_t)g * NN + d) * BKT + slot] = src[e];
}

// ---------------- gathers: wave-per-node, masked 8-wide groups, dinv on the fly ----------------
__global__ __launch_bounds__(256) void gather_agg_f32(
    const float* __restrict__ x_all, const int* __restrict__ cnt_all,
    const int* __restrict__ bucket, uint* __restrict__ agg_all)
{
    int g = blockIdx.y;
    int wv = threadIdx.x >> 6, lane = threadIdx.x & 63;
    int n = blockIdx.x * 4 + wv;
    const float2* x = (const float2*)(x_all + (size_t)g * NN * FOBS);
    const int* cnt = cnt_all + (size_t)g * NN;
    const int* bkt = bucket + ((size_t)g * NN + n) * BKT;

    int cn = cnt[n];
    float wn = rsqrtf((float)cn + 1.0f);
    int deg = min(cn, BKT);

    float2 self = x[(size_t)n * 64 + lane];
    float ax = wn * wn * self.x, ay = wn * wn * self.y;

    for (int i = 0; i < deg; i += 8) {
        int last = deg - 1;
        int s0 = bkt[i];
        int s1 = bkt[min(i + 1, last)], s2 = bkt[min(i + 2, last)], s3 = bkt[min(i + 3, last)];
        int s4 = bkt[min(i + 4, last)], s5 = bkt[min(i + 5, last)], s6 = bkt[min(i + 6, last)];
        int s7 = bkt[min(i + 7, last)];
        float w0 = rsqrtf((float)cnt[s0] + 1.0f) * wn;
        float w1 = (i + 1 < deg) ? rsqrtf((float)cnt[s1] + 1.0f) * wn : 0.0f;
        float w2 = (i + 2 < deg) ? rsqrtf((float)cnt[s2] + 1.0f) * wn : 0.0f;
        float w3 = (i + 3 < deg) ? rsqrtf((float)cnt[s3] + 1.0f) * wn : 0.0f;
        float w4 = (i + 4 < deg) ? rsqrtf((float)cnt[s4] + 1.0f) * wn : 0.0f;
        float w5 = (i + 5 < deg) ? rsqrtf((float)cnt[s5] + 1.0f) * wn : 0.0f;
        float w6 = (i + 6 < deg) ? rsqrtf((float)cnt[s6] + 1.0f) * wn : 0.0f;
        float w7 = (i + 7 < deg) ? rsqrtf((float)cnt[s7] + 1.0f) * wn : 0.0f;
        float2 r0 = x[(size_t)s0 * 64 + lane], r1 = x[(size_t)s1 * 64 + lane];
        float2 r2 = x[(size_t)s2 * 64 + lane], r3 = x[(size_t)s3 * 64 + lane];
        float2 r4 = x[(size_t)s4 * 64 + lane], r5 = x[(size_t)s5 * 64 + lane];
        float2 r6 = x[(size_t)s6 * 64 + lane], r7 = x[(size_t)s7 * 64 + lane];
        ax += w0 * r0.x + w1 * r1.x + w2 * r2.x + w3 * r3.x
            + w4 * r4.x + w5 * r5.x + w6 * r6.x + w7 * r7.x;
        ay += w0 * r0.y + w1 * r1.y + w2 * r2.y + w3 * r3.y
            + w4 * r4.y + w5 * r5.y + w6 * r6.y + w7 * r7.y;
    }
    agg_all[((size_t)g * NN + n) * 64 + lane] = (uint)f2b(ax) | ((uint)f2b(ay) << 16);
}

__global__ __launch_bounds__(256) void gather_agg_b256(
    const uint2* __restrict__ xb_all, const int* __restrict__ cnt_all,
    const int* __restrict__ bucket, uint2* __restrict__ agg_all)
{
    int g = blockIdx.y;
    int wv = threadIdx.x >> 6, lane = threadIdx.x & 63;
    int n = blockIdx.x * 4 + wv;
    const uint2* xb = xb_all + (size_t)g * NN * 64;
    const int* cnt = cnt_all + (size_t)g * NN;
    const int* bkt = bucket + ((size_t)g * NN + n) * BKT;

    int cn = cnt[n];
    float wn = rsqrtf((float)cn + 1.0f);
    int deg = min(cn, BKT);

    uint2 u = xb[(size_t)n * 64 + lane];
    float w2s = wn * wn;
    float a0 = w2s * blo(u.x), a1 = w2s * bhi(u.x), a2 = w2s * blo(u.y), a3 = w2s * bhi(u.y);

    for (int i = 0; i < deg; i += 8) {
        int last = deg - 1;
        int s0 = bkt[i];
        int s1 = bkt[min(i + 1, last)], s2 = bkt[min(i + 2, last)], s3 = bkt[min(i + 3, last)];
        int s4 = bkt[min(i + 4, last)], s5 = bkt[min(i + 5, last)], s6 = bkt[min(i + 6, last)];
        int s7 = bkt[min(i + 7, last)];
        float w0 = rsqrtf((float)cnt[s0] + 1.0f) * wn;
        float w1 = (i + 1 < deg) ? rsqrtf((float)cnt[s1] + 1.0f) * wn : 0.0f;
        float w2 = (i + 2 < deg) ? rsqrtf((float)cnt[s2] + 1.0f) * wn : 0.0f;
        float w3 = (i + 3 < deg) ? rsqrtf((float)cnt[s3] + 1.0f) * wn : 0.0f;
        float w4 = (i + 4 < deg) ? rsqrtf((float)cnt[s4] + 1.0f) * wn : 0.0f;
        float w5 = (i + 5 < deg) ? rsqrtf((float)cnt[s5] + 1.0f) * wn : 0.0f;
        float w6 = (i + 6 < deg) ? rsqrtf((float)cnt[s6] + 1.0f) * wn : 0.0f;
        float w7 = (i + 7 < deg) ? rsqrtf((float)cnt[s7] + 1.0f) * wn : 0.0f;
        uint2 r0 = xb[(size_t)s0 * 64 + lane], r1 = xb[(size_t)s1 * 64 + lane];
        uint2 r2 = xb[(size_t)s2 * 64 + lane], r3 = xb[(size_t)s3 * 64 + lane];
        uint2 r4 = xb[(size_t)s4 * 64 + lane], r5 = xb[(size_t)s5 * 64 + lane];
        uint2 r6 = xb[(size_t)s6 * 64 + lane], r7 = xb[(size_t)s7 * 64 + lane];
        a0 += w0 * blo(r0.x) + w1 * blo(r1.x) + w2 * blo(r2.x) + w3 * blo(r3.x)
            + w4 * blo(r4.x) + w5 * blo(r5.x) + w6 * blo(r6.x) + w7 * blo(r7.x);
        a1 += w0 * bhi(r0.x) + w1 * bhi(r1.x) + w2 * bhi(r2.x) + w3 * bhi(r3.x)
            + w4 * bhi(r4.x) + w5 * bhi(r5.x) + w6 * bhi(r6.x) + w7 * bhi(r7.x);
        a2 += w0 * blo(r0.y) + w1 * blo(r1.y) + w2 * blo(r2.y) + w3 * blo(r3.y)
            + w4 * blo(r4.y) + w5 * blo(r5.y) + w6 * blo(r6.y) + w7 * blo(r7.y);
        a3 += w0 * bhi(r0.y) + w1 * bhi(r1.y) + w2 * bhi(r2.y) + w3 * bhi(r3.y)
            + w4 * bhi(r4.y) + w5 * bhi(r5.y) + w6 * bhi(r6.y) + w7 * bhi(r7.y);
    }
    uint2 o;
    o.x = (uint)f2b(a0) | ((uint)f2b(a1) << 16);
    o.y = (uint)f2b(a2) | ((uint)f2b(a3) << 16);
    agg_all[((size_t)g * NN + n) * 64 + lane] = o;
}

// ---------------- MFMA GEMM (layer 1, batched via blockIdx.z) ----------------
__global__ __launch_bounds__(256) void mfma_gemm(
    const ushort* __restrict__ A_all, const ushort* __restrict__ BT,
    const float* __restrict__ bias, ushort* __restrict__ C_all,
    int M, int N, int K, int relu)
{
    __shared__ ushort As[128][72];
    __shared__ ushort Bs[128][72];

    int g = blockIdx.z;
    const ushort* A = A_all + (size_t)g * M * K;
    ushort* C = C_all + (size_t)g * M * N;

    int t = threadIdx.x;
    int bn = blockIdx.x, bm = blockIdx.y;
    int lane = t & 63, w = t >> 6;
    int wm = w >> 1, wn = w & 1;
    int l15 = lane & 15, quad = lane >> 4;

    f32x4 acc[4][4] = {};

    int srow = t >> 3, scol = (t & 7) * 8;
    const ushort* Abase = A + (size_t)(bm * 128) * K;
    const ushort* Bbase = BT + (size_t)(bn * 128) * K;

    for (int k0 = 0; k0 < K; k0 += 64) {
#pragma unroll
        for (int i = 0; i < 4; ++i) {
            int row = srow + 32 * i;
            *(uint4*)&As[row][scol] = *(const uint4*)(Abase + (size_t)row * K + k0 + scol);
        }
#pragma unroll
        for (int i = 0; i < 4; ++i) {
            int row = srow + 32 * i;
            *(uint4*)&Bs[row][scol] = *(const uint4*)(Bbase + (size_t)row * K + k0 + scol);
        }
        __syncthreads();
#pragma unroll
        for (int kk = 0; kk < 64; kk += 32) {
            frag8 af[4], bf[4];
#pragma unroll
            for (int i = 0; i < 4; ++i)
                af[i] = *(const frag8*)&As[wm * 64 + i * 16 + l15][kk + quad * 8];
#pragma unroll
            for (int j = 0; j < 4; ++j)
                bf[j] = *(const frag8*)&Bs[wn * 64 + j * 16 + l15][kk + quad * 8];
#pragma unroll
            for (int i = 0; i < 4; ++i)
#pragma unroll
                for (int j = 0; j < 4; ++j)
                    acc[i][j] = __builtin_amdgcn_mfma_f32_16x16x32_bf16(af[i], bf[j], acc[i][j], 0, 0, 0);
        }
        __syncthreads();
    }

#pragma unroll
    for (int i = 0; i < 4; ++i) {
#pragma unroll
        for (int j = 0; j < 4; ++j) {
            int col = bn * 128 + wn * 64 + j * 16 + l15;
            float bcol = bias[col];
#pragma unroll
            for (int r = 0; r < 4; ++r) {
                int row = bm * 128 + wm * 64 + i * 16 + quad * 4 + r;
                float v = acc[i][j][r] + bcol;
                if (relu) v = fmaxf(v, 0.0f);
                C[(size_t)row * N + col] = f2b(v);
            }
        }
    }
}

// ---------------- fused layer-2 GEMM + heads (v1: 2 blocks/CU, 8 waves/CU) ----------------
__global__ __launch_bounds__(256) void gemm2_heads(
    const ushort* __restrict__ hagg_all,  // [g][NN][FH] bf16
    const ushort* __restrict__ W1T,       // [FOUT][FH] bf16
    const float*  __restrict__ b1,        // [FOUT]
    const ushort* __restrict__ WT19,      // [19][FOUT] bf16
    float* __restrict__ partial)          // [2][BB][NN][P20] f32
{
    __shared__ __align__(16) ushort smem[2 * 128 * 72];  // As|Bs; reused as Ctile
    __shared__ __align__(16) ushort wt[20][136];         // WT19 slice, row19=0

    ushort* As = smem;
    ushort* Bs = smem + 128 * 72;
    ushort* Ct = smem;                                   // [128][136]

    int bm = blockIdx.x, sp = blockIdx.y, g = blockIdx.z;
    int t = threadIdx.x;
    int lane = t & 63, w = t >> 6;
    int wm = w >> 1, wn = w & 1;
    int l15 = lane & 15, quad = lane >> 4;
    int srow = t >> 3, scol = (t & 7) * 8;

    const ushort* A0 = hagg_all + ((size_t)g * NN + bm * 128) * FH;

    if (t < 136) wt[19][t] = 0;

    f32x4 hacc[2][2] = {};

    for (int bi = 0; bi < 4; ++bi) {
        int bn = sp * 4 + bi;
        __syncthreads();

        for (int idx = t; idx < 19 * 16; idx += 256) {
            int row = idx >> 4, c8 = (idx & 15) * 8;
            *(uint4*)&wt[row][c8] = *(const uint4*)(WT19 + (size_t)row * FOUT + bn * 128 + c8);
        }

        f32x4 acc[4][4] = {};
        const ushort* Bbase = W1T + (size_t)(bn * 128) * FH;

        for (int k0 = 0; k0 < FH; k0 += 64) {
#pragma unroll
            for (int i = 0; i < 4; ++i) {
                int row = srow + 32 * i;
                *(uint4*)&As[row * 72 + scol] = *(const uint4*)(A0 + (size_t)row * FH + k0 + scol);
                *(uint4*)&Bs[row * 72 + scol] = *(const uint4*)(Bbase + (size_t)row * FH + k0 + scol);
            }
            __syncthreads();
#pragma unroll
            for (int kk = 0; kk < 64; kk += 32) {
                frag8 af[4], bf[4];
#pragma unroll
                for (int i = 0; i < 4; ++i)
                    af[i] = *(const frag8*)&As[(wm * 64 + i * 16 + l15) * 72 + kk + quad * 8];
#pragma unroll
                for (int j = 0; j < 4; ++j)
                    bf[j] = *(const frag8*)&Bs[(wn * 64 + j * 16 + l15) * 72 + kk + quad * 8];
#pragma unroll
                for (int i = 0; i < 4; ++i)
#pragma unroll
                    for (int j = 0; j < 4; ++j)
                        acc[i][j] = __builtin_amdgcn_mfma_f32_16x16x32_bf16(af[i], bf[j], acc[i][j], 0, 0, 0);
            }
            __syncthreads();
        }

#pragma unroll
        for (int j = 0; j < 4; ++j) {
            int colL = wn * 64 + j * 16 + l15;
            float bcol = b1[bn * 128 + colL];
#pragma unroll
            for (int i = 0; i < 4; ++i) {
                int rowL = wm * 64 + i * 16 + quad * 4;
#pragma unroll
                for (int r = 0; r < 4; ++r) {
                    float v = fmaxf(acc[i][j][r] + bcol, 0.0f);
                    Ct[(size_t)(rowL + r) * 136 + colL] = f2b(v);
                }
            }
        }
        __syncthreads();

        int r1 = (l15 < 3) ? (16 + l15) : 19;
#pragma unroll
        for (int kk = 0; kk < 128; kk += 32) {
            frag8 b0 = *(const frag8*)&wt[l15][kk + quad * 8];
            frag8 bO = *(const frag8*)&wt[r1][kk + quad * 8];
#pragma unroll
            for (int mt = 0; mt < 2; ++mt) {
                int row = (w * 2 + mt) * 16 + l15;
                frag8 af = *(const frag8*)&Ct[(size_t)row * 136 + kk + quad * 8];
                hacc[mt][0] = __builtin_amdgcn_mfma_f32_16x16x32_bf16(af, b0, hacc[mt][0], 0, 0, 0);
                hacc[mt][1] = __builtin_amdgcn_mfma_f32_16x16x32_bf16(af, bO, hacc[mt][1], 0, 0, 0);
            }
        }
    }

#pragma unroll
    for (int mt = 0; mt < 2; ++mt) {
#pragma unroll
        for (int r = 0; r < 4; ++r) {
            int node = bm * 128 + (w * 2 + mt) * 16 + quad * 4 + r;
            size_t base = ((size_t)(sp * BB + g) * NN + node) * P20;
            partial[base + l15] = hacc[mt][0][r];
            if (l15 < 3) partial[base + 16 + l15] = hacc[mt][1][r];
        }
    }
}

// ---------------- heads combine: out = p0 + p1 + bias ----------------
__global__ void heads_combine(const float* __restrict__ partial,
                              const float* __restrict__ bl, const float* __restrict__ bv,
                              float* __restrict__ out_logits, float* __restrict__ out_values) {
    int i = blockIdx.x * blockDim.x + threadIdx.x;
    if (i >= BB * NN * 19) return;
    int o = i % 19;
    int gn = i / 19;
    float v = partial[(size_t)gn * P20 + o] + partial[((size_t)BB * NN + gn) * P20 + o];
    if (o < NLOG) out_logits[(size_t)gn * NLOG + o] = v + bl[o];
    else          out_values[gn] = v + bv[0];
}

// ---------------- launcher ----------------
extern "C" void kernel_launch(void* const* d_in, const int* in_sizes, int n_in,
                              void* d_out, int out_size, void* d_ws, size_t ws_size,
                              hipStream_t stream) {
    const float* nodes = (const float*)d_in[0];
    const int*   edges = (const int*)d_in[1];
    const float* W0 = (const float*)d_in[2];
    const float* b0 = (const float*)d_in[3];
    const float* W1 = (const float*)d_in[4];
    const float* b1 = (const float*)d_in[5];
    const float* Wl = (const float*)d_in[6];
    const float* bl = (const float*)d_in[7];
    const float* Wv = (const float*)d_in[8];
    const float* bv = (const float*)d_in[9];

    float* out_logits = (float*)d_out;
    float* out_values = out_logits + (size_t)BB * NN * NLOG;

    char* ws = (char*)d_ws;
    int*    cursor  = (int*)(ws);                     // 128 KB (becomes cnt)
    ushort* W0T     = (ushort*)(ws + (128 << 10));    // 64 KB
    ushort* W1T     = (ushort*)(ws + (192 << 10));    // 512 KB
    ushort* WT19    = (ushort*)(ws + (704 << 10));    // 38 KB
    int*    bucket  = (int*)(ws + (1u << 20));        // 8 MB   [B,N,64]
    ushort* xagg_b  = (ushort*)(ws + (9u << 20));     // 8 MB   [B,N,128]
    ushort* h1b     = (ushort*)(ws + (17u << 20));    // 16 MB  [B,N,256]
    ushort* hagg_b  = (ushort*)(ws + (33u << 20));    // 16 MB  [B,N,256]
    float*  partial = (float*)(ws + (49u << 20));     // 5.25 MB [2,B,N,20]
    // total ~55 MB

    // 1. prep
    prep_kernel<<<(PREP_TOTAL + 255) / 256, 256, 0, stream>>>(
        W0, W0T, W1, W1T, Wl, Wv, WT19, cursor);

    // 2. bucket fill
    bucket_fill<<<1024, 256, 0, stream>>>(edges, cursor, bucket);

    // 3. layer-1 aggregation
    gather_agg_f32<<<dim3(NN / 4, BB), 256, 0, stream>>>(nodes, cursor, bucket, (uint*)xagg_b);

    // 4. layer-1 GEMM
    mfma_gemm<<<dim3(FH / 128, NN / 128, BB), 256, 0, stream>>>(
        xagg_b, W0T, b0, h1b, NN, FH, FOBS, 1);

    // 5. layer-2 aggregation
    gather_agg_b256<<<dim3(NN / 4, BB), 256, 0, stream>>>((const uint2*)h1b, cursor, bucket,
                                                          (uint2*)hagg_b);

    // 6. fused layer-2 GEMM + heads (h2 stays in LDS)
    gemm2_heads<<<dim3(NN / 128, 2, BB), 256, 0, stream>>>(hagg_b, W1T, b1, WT19, partial);

    // 7. combine
    heads_combine<<<(BB * NN * 19 + 255) / 256, 256, 0, stream>>>(partial, bl, bv,
                                                                  out_logits, out_values);
}